// Round 3
// baseline (1360.088 us; speedup 1.0000x reference)
//
#include <hip/hip_runtime.h>

// KMeans soft-assignment: out[n,k] = softmax_k( -dist(x_n, c_k)^2 / 0.1 )
// logit_k = 20 * dot(x_n, c_k) - 10 * ||c_k||^2   (||x_n||^2 cancels in softmax)
//
// Structure: 512-thread blocks; thread k owns cluster k with its centroid row
// resident in 64 VGPRs. x-row loads are block-uniform -> scalar loads (SGPR),
// so the dot-product inner loop is pure v_fmac_f32. Softmax over the 512
// logits (one per thread) via wave shfl reduce + 8-wave LDS combine,
// batched RB=4 rows per barrier set.

constexpr int KC = 512;   // clusters
constexpr int D  = 64;    // feature dim
constexpr int RB = 4;     // rows per batch

__global__ __launch_bounds__(512, 4)
void kmeans_soft_assign(const float* __restrict__ x,
                        const float* __restrict__ cent,
                        float* __restrict__ out,
                        int n_rows, int rows_per_block)
{
    const int tid  = threadIdx.x;        // == cluster id
    const int wave = tid >> 6;
    const int lane = tid & 63;

    // Centroid row for this thread's cluster -> registers (one-time, L2-cached)
    float c[D];
    const float4* cv = reinterpret_cast<const float4*>(cent + tid * D);
    #pragma unroll
    for (int i = 0; i < D / 4; ++i) {
        float4 v = cv[i];
        c[4*i+0] = v.x; c[4*i+1] = v.y; c[4*i+2] = v.z; c[4*i+3] = v.w;
    }
    float csq = 0.f;
    #pragma unroll
    for (int d = 0; d < D; ++d) csq = fmaf(c[d], c[d], csq);
    const float bias = -10.0f * csq;     // -10*||c||^2

    __shared__ float red_max[RB][8];
    __shared__ float red_sum[RB][8];

    const int row0    = blockIdx.x * rows_per_block;
    const int row_lim = min(row0 + rows_per_block, n_rows);

    for (int rb = row0; rb < row_lim; rb += RB) {
        const int rcount = min(RB, row_lim - rb);   // uniform across block

        float acc[RB];
        #pragma unroll
        for (int r = 0; r < RB; ++r) acc[r] = 0.f;

        // Dot products: x values are block-uniform -> scalar loads.
        // Clamp row index so tail batches never read OOB (results unused).
        const float* xr = x + (size_t)rb * D;
        int roff[RB];
        #pragma unroll
        for (int r = 0; r < RB; ++r)
            roff[r] = (r < rcount) ? r * D : 0;

        #pragma unroll
        for (int d = 0; d < D; ++d) {
            #pragma unroll
            for (int r = 0; r < RB; ++r)
                acc[r] = fmaf(xr[roff[r] + d], c[d], acc[r]);
        }

        float logit[RB], m[RB], p[RB];
        #pragma unroll
        for (int r = 0; r < RB; ++r) logit[r] = fmaf(20.0f, acc[r], bias);

        __syncthreads();   // B0: prior iteration's red_* reads complete
        #pragma unroll
        for (int r = 0; r < RB; ++r) {
            float v = logit[r];
            #pragma unroll
            for (int off = 32; off; off >>= 1)
                v = fmaxf(v, __shfl_xor(v, off));
            m[r] = v;
            if (lane == 0) red_max[r][wave] = v;
        }
        __syncthreads();   // B1: maxes visible
        #pragma unroll
        for (int r = 0; r < RB; ++r) {
            float gm = red_max[r][0];
            #pragma unroll
            for (int w = 1; w < 8; ++w) gm = fmaxf(gm, red_max[r][w]);
            p[r] = __expf(logit[r] - gm);
            float v = p[r];
            #pragma unroll
            for (int off = 32; off; off >>= 1)
                v += __shfl_xor(v, off);
            if (lane == 0) red_sum[r][wave] = v;
        }
        __syncthreads();   // B2: sums visible
        #pragma unroll
        for (int r = 0; r < RB; ++r) {
            float t = 0.f;
            #pragma unroll
            for (int w = 0; w < 8; ++w) t += red_sum[r][w];
            if (r < rcount)
                out[(size_t)(rb + r) * KC + tid] = p[r] * __builtin_amdgcn_rcpf(t);
        }
    }
}

extern "C" void kernel_launch(void* const* d_in, const int* in_sizes, int n_in,
                              void* d_out, int out_size, void* d_ws, size_t ws_size,
                              hipStream_t stream) {
    const float* x    = (const float*)d_in[0];
    const float* cent = (const float*)d_in[1];
    float* out        = (float*)d_out;

    const int n_rows = in_sizes[0] / D;          // 262144 for the bench shape
    const int rpb    = 128;                      // rows per block
    const int blocks = (n_rows + rpb - 1) / rpb; // 2048 blocks -> 8 blocks/CU queued

    hipLaunchKernelGGL(kmeans_soft_assign, dim3(blocks), dim3(512), 0, stream,
                       x, cent, out, n_rows, rpb);
}

// Round 9
// 695.563 us; speedup vs baseline: 1.9554x; 1.9554x over previous
//
#include <hip/hip_runtime.h>

// Soft k-means assignment via split-bf16 MFMA GEMM + fused softmax.
//   logit[n,k] = 20*dot(x_n,c_k) - 10*||c_k||^2   (||x_n||^2 cancels in softmax)
// x -> (xh, xl) bf16 pair, c -> (ch, cl) bf16 pair.
//   x*c ~= xh*ch + xl*ch + xh*cl      (xl*cl ~ 2^-18 rel, dropped)
// Round-6 failure (absmax 0.443) was exactly the missing cross terms
// (xh*cl + xl*ch ~ 0.02 in the dot * 20 temperature = 0.4 logit error);
// this version pairs the k-slots explicitly: 6 MFMA K-steps per N-tile.
// C/D layout: m89-verified col=lane&15, row=4*(lane>>4)+reg.
//
// Block = 512 threads (8 waves). Per block-tile: 16 rows x 512 clusters.
// Wave w owns clusters [64w, 64w+64) as 4 N-tiles of 16; B-fragments (64 VGPR)
// and bias (-10*||c||^2) are kernel-lifetime register-resident (they feed MFMA
// directly, so the allocator cannot sink them like round-0's c[64] array).
// Epilogue: logits -> LDS [16][516] (pad -> 2-way = free), block softmax,
// coalesced dwordx4 stores (2 KB/instr/wave).

constexpr int KC   = 512;   // clusters
constexpr int D    = 64;    // feature dim
constexpr int RT   = 16;    // rows per block-tile
constexpr int NT   = 4;     // 16-cluster N-tiles per wave
constexpr int LSTR = 516;   // LDS row stride in f32 (+4 pad)

typedef float f32x4 __attribute__((ext_vector_type(4)));
typedef short s16x8 __attribute__((ext_vector_type(8)));

__device__ inline unsigned short bf16_rn(float f) {
    unsigned u = __builtin_bit_cast(unsigned, f);
    u += 0x7fffu + ((u >> 16) & 1u);
    return (unsigned short)(u >> 16);
}
__device__ inline float bf16f(unsigned short h) {
    unsigned u = (unsigned)h << 16;
    return __builtin_bit_cast(float, u);
}
__device__ inline void split2(float f, unsigned short& hi, unsigned short& lo) {
    hi = bf16_rn(f);
    lo = bf16_rn(f - bf16f(hi));
}

// Pack 16 floats (cols 8g..8g+7, 32+8g..32+8g+7) into 4 K-step fragments:
// fr[0]=hi of d[0:32) slice, fr[1]=hi of d[32:64) slice, fr[2]/fr[3]=lo same.
// A and B use the identical (g,j)->k packing, so HW pairing is consistent.
__device__ inline void pack_frags(const f32x4& v0, const f32x4& v1,
                                  const f32x4& v2, const f32x4& v3,
                                  s16x8 fr[4]) {
    #pragma unroll
    for (int j = 0; j < 4; ++j) {
        unsigned short h, l;
        split2(v0[j], h, l); fr[0][j]     = (short)h; fr[2][j]     = (short)l;
        split2(v1[j], h, l); fr[0][4 + j] = (short)h; fr[2][4 + j] = (short)l;
        split2(v2[j], h, l); fr[1][j]     = (short)h; fr[3][j]     = (short)l;
        split2(v3[j], h, l); fr[1][4 + j] = (short)h; fr[3][4 + j] = (short)l;
    }
}

__global__ __launch_bounds__(512)
void kmeans_mfma(const float* __restrict__ x,
                 const float* __restrict__ cent,
                 float* __restrict__ out,
                 int n_rows, int tiles_per_block)
{
    const int tid  = threadIdx.x;
    const int wave = tid >> 6;
    const int lane = tid & 63;
    const int l15  = lane & 15;
    const int g    = lane >> 4;

    __shared__ float lds[RT * LSTR];

    // ---- one-time: centroid B-fragments + bias, register-resident ----
    s16x8 fb[NT][4];
    float bias[NT];
    #pragma unroll
    for (int t = 0; t < NT; ++t) {
        const int cl = wave * 64 + t * 16 + l15;
        const float* cr = cent + cl * D;
        f32x4 b0 = *(const f32x4*)(cr + 8 * g);
        f32x4 b1 = *(const f32x4*)(cr + 8 * g + 4);
        f32x4 b2 = *(const f32x4*)(cr + 32 + 8 * g);
        f32x4 b3 = *(const f32x4*)(cr + 32 + 8 * g + 4);
        float csq = 0.f;
        #pragma unroll
        for (int j = 0; j < 4; ++j)
            csq += b0[j]*b0[j] + b1[j]*b1[j] + b2[j]*b2[j] + b3[j]*b3[j];
        // lanes l, l^16, l^32, l^48 share a cluster and cover disjoint cols
        csq += __shfl_xor(csq, 16);
        csq += __shfl_xor(csq, 32);
        bias[t] = -10.0f * csq;
        pack_frags(b0, b1, b2, b3, fb[t]);
    }

    const int tile0 = blockIdx.x * tiles_per_block;

    f32x4 a0, a1, a2, a3;
    auto loadA = [&](int tile, f32x4& A0, f32x4& A1, f32x4& A2, f32x4& A3) {
        int row = tile * RT + l15;
        row = min(row, n_rows - 1);
        const float* xr = x + (size_t)row * D;
        A0 = *(const f32x4*)(xr + 8 * g);
        A1 = *(const f32x4*)(xr + 8 * g + 4);
        A2 = *(const f32x4*)(xr + 32 + 8 * g);
        A3 = *(const f32x4*)(xr + 32 + 8 * g + 4);
    };

    if (tile0 * RT < n_rows) loadA(tile0, a0, a1, a2, a3);

    for (int tt = 0; tt < tiles_per_block; ++tt) {
        const int tile  = tile0 + tt;
        const int rbase = tile * RT;
        if (rbase >= n_rows) break;          // block-uniform

        // convert current x-tile to A fragments
        s16x8 fa[4];
        pack_frags(a0, a1, a2, a3, fa);

        // prefetch next tile's floats (hides HBM latency under MFMA+softmax)
        f32x4 n0 = a0, n1 = a1, n2 = a2, n3 = a3;
        const bool havenext =
            (tt + 1 < tiles_per_block) && ((tile + 1) * RT < n_rows);
        if (havenext) loadA(tile + 1, n0, n1, n2, n3);

        // ---- GEMM: per N-tile, 6 K-steps: hh(2) + lh(2) + hl(2) ----
        f32x4 acc[NT] = {};
        #pragma unroll
        for (int t = 0; t < NT; ++t) {
            acc[t] = __builtin_amdgcn_mfma_f32_16x16x32_bf16(fa[0], fb[t][0], acc[t], 0, 0, 0); // xh0*ch0
            acc[t] = __builtin_amdgcn_mfma_f32_16x16x32_bf16(fa[1], fb[t][1], acc[t], 0, 0, 0); // xh1*ch1
            acc[t] = __builtin_amdgcn_mfma_f32_16x16x32_bf16(fa[2], fb[t][0], acc[t], 0, 0, 0); // xl0*ch0
            acc[t] = __builtin_amdgcn_mfma_f32_16x16x32_bf16(fa[3], fb[t][1], acc[t], 0, 0, 0); // xl1*ch1
            acc[t] = __builtin_amdgcn_mfma_f32_16x16x32_bf16(fa[0], fb[t][2], acc[t], 0, 0, 0); // xh0*cl0
            acc[t] = __builtin_amdgcn_mfma_f32_16x16x32_bf16(fa[1], fb[t][3], acc[t], 0, 0, 0); // xh1*cl1
        }

        // ---- epilogue: logits -> LDS ----
        #pragma unroll
        for (int t = 0; t < NT; ++t) {
            const int col = wave * 64 + t * 16 + l15;
            #pragma unroll
            for (int r = 0; r < 4; ++r) {
                const int row = g * 4 + r;   // m89-verified C/D row mapping
                lds[row * LSTR + col] = fmaf(20.0f, acc[t][r], bias[t]);
            }
        }
        __syncthreads();

        // ---- softmax: wave w handles rows 2w, 2w+1 ----
        #pragma unroll
        for (int rr = 0; rr < 2; ++rr) {
            const int row = 2 * wave + rr;
            const float* lr = &lds[row * LSTR + lane * 8];
            f32x4 v0 = *(const f32x4*)lr;
            f32x4 v1 = *(const f32x4*)(lr + 4);
            float m = v0[0];
            #pragma unroll
            for (int j = 1; j < 4; ++j) m = fmaxf(m, v0[j]);
            #pragma unroll
            for (int j = 0; j < 4; ++j) m = fmaxf(m, v1[j]);
            #pragma unroll
            for (int off = 32; off; off >>= 1)
                m = fmaxf(m, __shfl_xor(m, off));
            float p[8], s = 0.f;
            #pragma unroll
            for (int j = 0; j < 4; ++j) { p[j]     = __expf(v0[j] - m); s += p[j]; }
            #pragma unroll
            for (int j = 0; j < 4; ++j) { p[4 + j] = __expf(v1[j] - m); s += p[4 + j]; }
            #pragma unroll
            for (int off = 32; off; off >>= 1)
                s += __shfl_xor(s, off);
            const float rinv = __builtin_amdgcn_rcpf(s);
            f32x4 o0, o1;
            #pragma unroll
            for (int j = 0; j < 4; ++j) { o0[j] = p[j] * rinv; o1[j] = p[4 + j] * rinv; }
            const int grow = rbase + row;
            if (grow < n_rows) {
                float* dp = out + (size_t)grow * KC + lane * 8;
                *(f32x4*)dp       = o0;
                *(f32x4*)(dp + 4) = o1;      // 2 KB contiguous per instr per wave
            }
        }
        __syncthreads();   // reads done before next tile's logit writes

        a0 = n0; a1 = n1; a2 = n2; a3 = n3;
    }
}

extern "C" void kernel_launch(void* const* d_in, const int* in_sizes, int n_in,
                              void* d_out, int out_size, void* d_ws, size_t ws_size,
                              hipStream_t stream) {
    const float* x    = (const float*)d_in[0];
    const float* cent = (const float*)d_in[1];
    float* out        = (float*)d_out;

    const int n_rows = in_sizes[0] / D;                   // 262144 for bench shape
    const int n_tiles = (n_rows + RT - 1) / RT;           // 16384
    const int tiles_per_block = 4;
    const int blocks = (n_tiles + tiles_per_block - 1) / tiles_per_block;  // 4096

    hipLaunchKernelGGL(kmeans_mfma, dim3(blocks), dim3(512), 0, stream,
                       x, cent, out, n_rows, tiles_per_block);
}

// Round 12
// 688.743 us; speedup vs baseline: 1.9747x; 1.0099x over previous
//
#include <hip/hip_runtime.h>

// Soft k-means assignment via split-bf16 MFMA GEMM + fused softmax.
//   logit[n,k] = 20*dot(x_n,c_k) - 10*||c_k||^2   (||x_n||^2 cancels in softmax)
// x -> (xh, xl) bf16 pair, c -> (ch, cl) bf16 pair.
//   x*c ~= xh*ch + xl*ch + xh*cl      (xl*cl ~ 2^-18 rel, dropped)
// Verified round 9: passed, absmax 3.9e-3, kernel ~270 us (dur_us 695 minus
// ~450 us harness re-poison fills).
//
// This round: occupancy. Round-9 build was ~150+ VGPR -> 1 block/CU (8 waves);
// all LDS/store latency exposed. Changes:
//   - no manual float prefetch (-16 VGPR; TLP hides the tile load instead)
//   - __launch_bounds__(512, 4): 4 waves/SIMD min -> <=128 VGPR -> 2 blocks/CU
//     (peak live estimate ~115 regs: fb 64 + bias 4 + a 16 + fa 16 + misc)
//   - tiles_per_block 8 (2048 blocks): halves per-CU centroid-prologue count
// C/D layout: m89-verified col=lane&15, row=4*(lane>>4)+reg.

constexpr int KC   = 512;   // clusters
constexpr int D    = 64;    // feature dim
constexpr int RT   = 16;    // rows per block-tile
constexpr int NT   = 4;     // 16-cluster N-tiles per wave
constexpr int LSTR = 516;   // LDS row stride in f32 (+4 pad)

typedef float f32x4 __attribute__((ext_vector_type(4)));
typedef short s16x8 __attribute__((ext_vector_type(8)));

__device__ inline unsigned short bf16_rn(float f) {
    unsigned u = __builtin_bit_cast(unsigned, f);
    u += 0x7fffu + ((u >> 16) & 1u);
    return (unsigned short)(u >> 16);
}
__device__ inline float bf16f(unsigned short h) {
    unsigned u = (unsigned)h << 16;
    return __builtin_bit_cast(float, u);
}
__device__ inline void split2(float f, unsigned short& hi, unsigned short& lo) {
    hi = bf16_rn(f);
    lo = bf16_rn(f - bf16f(hi));
}

// Pack 16 floats (cols 8g..8g+7, 32+8g..32+8g+7) into 4 K-step fragments:
// fr[0]=hi of d[0:32) slice, fr[1]=hi of d[32:64) slice, fr[2]/fr[3]=lo same.
// A and B use the identical (g,j)->k packing, so HW pairing is consistent.
__device__ inline void pack_frags(const f32x4& v0, const f32x4& v1,
                                  const f32x4& v2, const f32x4& v3,
                                  s16x8 fr[4]) {
    #pragma unroll
    for (int j = 0; j < 4; ++j) {
        unsigned short h, l;
        split2(v0[j], h, l); fr[0][j]     = (short)h; fr[2][j]     = (short)l;
        split2(v1[j], h, l); fr[0][4 + j] = (short)h; fr[2][4 + j] = (short)l;
        split2(v2[j], h, l); fr[1][j]     = (short)h; fr[3][j]     = (short)l;
        split2(v3[j], h, l); fr[1][4 + j] = (short)h; fr[3][4 + j] = (short)l;
    }
}

__global__ __launch_bounds__(512, 4)
void kmeans_mfma(const float* __restrict__ x,
                 const float* __restrict__ cent,
                 float* __restrict__ out,
                 int n_rows, int tiles_per_block)
{
    const int tid  = threadIdx.x;
    const int wave = tid >> 6;
    const int lane = tid & 63;
    const int l15  = lane & 15;
    const int g    = lane >> 4;

    __shared__ float lds[RT * LSTR];

    // ---- one-time: centroid B-fragments + bias, register-resident ----
    s16x8 fb[NT][4];
    float bias[NT];
    #pragma unroll
    for (int t = 0; t < NT; ++t) {
        const int cl = wave * 64 + t * 16 + l15;
        const float* cr = cent + cl * D;
        f32x4 b0 = *(const f32x4*)(cr + 8 * g);
        f32x4 b1 = *(const f32x4*)(cr + 8 * g + 4);
        f32x4 b2 = *(const f32x4*)(cr + 32 + 8 * g);
        f32x4 b3 = *(const f32x4*)(cr + 32 + 8 * g + 4);
        float csq = 0.f;
        #pragma unroll
        for (int j = 0; j < 4; ++j)
            csq += b0[j]*b0[j] + b1[j]*b1[j] + b2[j]*b2[j] + b3[j]*b3[j];
        // lanes l, l^16, l^32, l^48 share a cluster and cover disjoint cols
        csq += __shfl_xor(csq, 16);
        csq += __shfl_xor(csq, 32);
        bias[t] = -10.0f * csq;
        pack_frags(b0, b1, b2, b3, fb[t]);
    }

    const int tile0 = blockIdx.x * tiles_per_block;

    for (int tt = 0; tt < tiles_per_block; ++tt) {
        const int tile  = tile0 + tt;
        const int rbase = tile * RT;
        if (rbase >= n_rows) break;          // block-uniform

        // load + pack this tile's x rows (no manual prefetch: 2 blocks/CU TLP
        // hides the latency; saves 16 VGPR)
        int row = rbase + l15;
        row = min(row, n_rows - 1);
        const float* xr = x + (size_t)row * D;
        f32x4 a0 = *(const f32x4*)(xr + 8 * g);
        f32x4 a1 = *(const f32x4*)(xr + 8 * g + 4);
        f32x4 a2 = *(const f32x4*)(xr + 32 + 8 * g);
        f32x4 a3 = *(const f32x4*)(xr + 32 + 8 * g + 4);
        s16x8 fa[4];
        pack_frags(a0, a1, a2, a3, fa);

        // ---- GEMM: per N-tile, 6 K-steps: hh(2) + lh(2) + hl(2) ----
        f32x4 acc[NT] = {};
        #pragma unroll
        for (int t = 0; t < NT; ++t) {
            acc[t] = __builtin_amdgcn_mfma_f32_16x16x32_bf16(fa[0], fb[t][0], acc[t], 0, 0, 0); // xh0*ch0
            acc[t] = __builtin_amdgcn_mfma_f32_16x16x32_bf16(fa[1], fb[t][1], acc[t], 0, 0, 0); // xh1*ch1
            acc[t] = __builtin_amdgcn_mfma_f32_16x16x32_bf16(fa[2], fb[t][0], acc[t], 0, 0, 0); // xl0*ch0
            acc[t] = __builtin_amdgcn_mfma_f32_16x16x32_bf16(fa[3], fb[t][1], acc[t], 0, 0, 0); // xl1*ch1
            acc[t] = __builtin_amdgcn_mfma_f32_16x16x32_bf16(fa[0], fb[t][2], acc[t], 0, 0, 0); // xh0*cl0
            acc[t] = __builtin_amdgcn_mfma_f32_16x16x32_bf16(fa[1], fb[t][3], acc[t], 0, 0, 0); // xh1*cl1
        }

        // ---- epilogue: logits -> LDS ----
        #pragma unroll
        for (int t = 0; t < NT; ++t) {
            const int col = wave * 64 + t * 16 + l15;
            #pragma unroll
            for (int r = 0; r < 4; ++r) {
                const int lrow = g * 4 + r;   // m89-verified C/D row mapping
                lds[lrow * LSTR + col] = fmaf(20.0f, acc[t][r], bias[t]);
            }
        }
        __syncthreads();

        // ---- softmax: wave w handles rows 2w, 2w+1 ----
        #pragma unroll
        for (int rr = 0; rr < 2; ++rr) {
            const int srow = 2 * wave + rr;
            const float* lr = &lds[srow * LSTR + lane * 8];
            f32x4 v0 = *(const f32x4*)lr;
            f32x4 v1 = *(const f32x4*)(lr + 4);
            float m = v0[0];
            #pragma unroll
            for (int j = 1; j < 4; ++j) m = fmaxf(m, v0[j]);
            #pragma unroll
            for (int j = 0; j < 4; ++j) m = fmaxf(m, v1[j]);
            #pragma unroll
            for (int off = 32; off; off >>= 1)
                m = fmaxf(m, __shfl_xor(m, off));
            float p[8], s = 0.f;
            #pragma unroll
            for (int j = 0; j < 4; ++j) { p[j]     = __expf(v0[j] - m); s += p[j]; }
            #pragma unroll
            for (int j = 0; j < 4; ++j) { p[4 + j] = __expf(v1[j] - m); s += p[4 + j]; }
            #pragma unroll
            for (int off = 32; off; off >>= 1)
                s += __shfl_xor(s, off);
            const float rinv = __builtin_amdgcn_rcpf(s);
            f32x4 o0, o1;
            #pragma unroll
            for (int j = 0; j < 4; ++j) { o0[j] = p[j] * rinv; o1[j] = p[4 + j] * rinv; }
            const int grow = rbase + srow;
            if (grow < n_rows) {
                float* dp = out + (size_t)grow * KC + lane * 8;
                *(f32x4*)dp       = o0;
                *(f32x4*)(dp + 4) = o1;      // 2 KB contiguous per instr per wave
            }
        }
        __syncthreads();   // reads done before next tile's logit writes
    }
}

extern "C" void kernel_launch(void* const* d_in, const int* in_sizes, int n_in,
                              void* d_out, int out_size, void* d_ws, size_t ws_size,
                              hipStream_t stream) {
    const float* x    = (const float*)d_in[0];
    const float* cent = (const float*)d_in[1];
    float* out        = (float*)d_out;

    const int n_rows = in_sizes[0] / D;                   // 262144 for bench shape
    const int n_tiles = (n_rows + RT - 1) / RT;           // 16384
    const int tiles_per_block = 8;
    const int blocks = (n_tiles + tiles_per_block - 1) / tiles_per_block;  // 2048

    hipLaunchKernelGGL(kmeans_mfma, dim3(blocks), dim3(512), 0, stream,
                       x, cent, out, n_rows, tiles_per_block);
}